// Round 9
// baseline (14134.903 us; speedup 1.0000x reference)
//
#include <hip/hip_runtime.h>
#include <hip/hip_bf16.h>
#include <hip/hip_cooperative_groups.h>

namespace cg = cooperative_groups;

typedef __bf16 bf16;
typedef __attribute__((ext_vector_type(8))) __bf16 bf16x8;
typedef __attribute__((ext_vector_type(4))) float floatx4;

#define HDIM 512
#define BATCH 4096
#define TSTEPS 16
#define KA 576      // A width: 63 x-feats + td + 512 h
#define NR 4096     // GEMM1 out cols: role-interleaved, 8 roles x 512 h

typedef const __attribute__((address_space(1))) void gvoid;
typedef __attribute__((address_space(3))) void svoid;

__device__ __forceinline__ float ftanh(float x) {
  float xx = fminf(fmaxf(x, -15.f), 15.f);
  float t = __expf(2.f * xx);
  return (t - 1.f) / (t + 1.f);
}
__device__ __forceinline__ float fsigm(float x) { return 1.0f / (1.0f + __expf(-x)); }

__device__ __forceinline__ float waveAllSum(float v) {
#pragma unroll
  for (int off = 32; off > 0; off >>= 1) v += __shfl_xor(v, off, 64);
  return v;
}

// ---------------------------------------------------------------------------
// Persistent cooperative kernel: 16 x (gemm1+gates -> sync -> gemm2 -> sync ->
// attention -> sync). 1024 blocks exactly (4/CU, 32 KB LDS, VGPR<=128 via
// launch_bounds). c state lives in registers across all 16 steps (stable
// block->tile mapping) -- cbuf is gone entirely.
// ---------------------------------------------------------------------------
__global__ __launch_bounds__(256, 4)
void persist_kernel(const bf16* __restrict__ xbuf, const float* __restrict__ tdT,
                    const bf16* __restrict__ wcombT,
                    const float* __restrict__ bvec, const float* __restrict__ WtT,
                    const float* __restrict__ bT,
                    bf16* __restrict__ hcur, bf16* __restrict__ hbuf,
                    bf16* __restrict__ histWa, bf16* __restrict__ histWe,
                    const bf16* __restrict__ wbwgT, const float* __restrict__ baPad,
                    const float* __restrict__ sWa, const float* __restrict__ sWe,
                    const float* __restrict__ va, const float* __restrict__ bh,
                    bf16* __restrict__ hWbG) {
  cg::grid_group grid = cg::this_grid();
  __shared__ __align__(16) bf16 As[128 * 64];  // 16 KB (phase A); tgs alias after K-loop
  __shared__ __align__(16) bf16 Bs[128 * 64];  // 16 KB

  const int tid = threadIdx.x;
  const int lane = tid & 63;
  const int wv = tid >> 6;
  const int wy = wv >> 1;
  const int wx = wv & 1;
  const int quad = lane >> 4;
  const int lr = lane & 15;
  const int bid = blockIdx.x;

  // phase A (gemm1) tile mapping: XCD swizzle, stable across steps
  const int xcd = bid & 7;
  const int p = bid >> 3;
  const int n_idx = (xcd << 2) | (p >> 5);
  const int m_idx = p & 31;
  const int m0 = m_idx * 128;
  const int n0 = n_idx * 128;
  const int g8 = lane >> 3;
  const int cl = (lane & 7) ^ g8;  // logical chunk fetched (phys chunk = lc ^ (row&7))

  // phase B (gemm2) tile mapping: 64 m-tiles x 16 n-tiles = 1024 blocks
  const int m0b = (bid >> 4) * 64;
  const int n0b = (bid & 15) * 64;

  const int hcol = (n0 >> 7) * 16 + lr;
  const float bvi = bvec[hcol], bvf = bvec[512 + hcol];
  const float bvo = bvec[1024 + hcol], bvc = bvec[1536 + hcol];
  const float wtt = WtT[hcol], bt_ = bT[hcol];

  float c_reg[4][4];  // persistent cell state for (m0+..., hcol), wx==0 lanes
#pragma unroll
  for (int i = 0; i < 4; ++i)
#pragma unroll
    for (int r = 0; r < 4; ++r) c_reg[i][r] = 0.f;

  for (int t = 0; t < TSTEPS; ++t) {
    // ================= phase A: gemm1 + gates =================
    {
      const bf16* A1 = xbuf + (size_t)t * BATCH * 64;
      bf16* waSlot = histWa + (size_t)((t + 15) & 15) * BATCH * HDIM;
      bf16* weSlot = histWe + (size_t)((t + 15) & 15) * BATCH * HDIM;
      floatx4 acc[4][4];
#pragma unroll
      for (int i = 0; i < 4; ++i)
#pragma unroll
        for (int j = 0; j < 4; ++j) {
          acc[i][j][0] = 0.f; acc[i][j][1] = 0.f; acc[i][j][2] = 0.f; acc[i][j][3] = 0.f;
        }
      for (int kt = 0; kt < KA / 64; ++kt) {
        const int kb = kt * 64;
        __syncthreads();
#pragma unroll
        for (int s = 0; s < 4; ++s) {  // A: 16 groups of 8 rows, 4 per wave
          const int g = wv * 4 + s;
          const int r = g * 8 + g8;
          const int col = kb + cl * 8;
          const bf16* src = (kt == 0) ? (A1 + (size_t)(m0 + r) * 64 + col)
                                      : (hbuf + (size_t)(m0 + r) * 512 + (col - 64));
          __builtin_amdgcn_global_load_lds((gvoid*)src, (svoid*)&As[g * 512], 16, 0, 0);
        }
#pragma unroll
        for (int s = 0; s < 4; ++s) {  // B: 16 groups of 8 rows, 4 per wave
          const int g = wv * 4 + s;
          const int r = g * 8 + g8;
          const bf16* src = wcombT + (size_t)(n0 + r) * KA + kb + cl * 8;
          __builtin_amdgcn_global_load_lds((gvoid*)src, (svoid*)&Bs[g * 512], 16, 0, 0);
        }
        __syncthreads();
#pragma unroll
        for (int s = 0; s < 2; ++s) {
          const int lc = s * 4 + quad;
          bf16x8 afr[4];
          bf16x8 bfr[4];
#pragma unroll
          for (int i = 0; i < 4; ++i) {
            const int r = wy * 64 + i * 16 + lr;
            afr[i] = *reinterpret_cast<const bf16x8*>(&As[r * 64 + ((lc ^ (r & 7)) << 3)]);
          }
#pragma unroll
          for (int j = 0; j < 4; ++j) {
            const int r = wx * 64 + j * 16 + lr;
            bfr[j] = *reinterpret_cast<const bf16x8*>(&Bs[r * 64 + ((lc ^ (r & 7)) << 3)]);
          }
#pragma unroll
          for (int i = 0; i < 4; ++i)
#pragma unroll
            for (int j = 0; j < 4; ++j)
              acc[i][j] =
                  __builtin_amdgcn_mfma_f32_16x16x32_bf16(afr[i], bfr[j], acc[i][j], 0, 0, 0);
        }
      }
      // fused gate epilogue; tg exchange via LDS aliased on As
      __syncthreads();
      float* tgs = reinterpret_cast<float*>(As);  // 128*17*4 = 8704 B
      if (wx == 1) {
#pragma unroll
        for (int i = 0; i < 4; ++i) {
#pragma unroll
          for (int r = 0; r < 4; ++r) {
            const int rl = wy * 64 + i * 16 + quad * 4 + r;
            const int m = m0 + rl;
            const size_t o = (size_t)m * 512 + hcol;
            tgs[rl * 17 + lr] = acc[i][0][r];
            waSlot[o] = (bf16)acc[i][1][r];
            weSlot[o] = (bf16)acc[i][2][r];
          }
        }
      }
      __syncthreads();
      if (wx == 0) {
#pragma unroll
        for (int i = 0; i < 4; ++i) {
#pragma unroll
          for (int r = 0; r < 4; ++r) {
            const int rl = wy * 64 + i * 16 + quad * 4 + r;
            const int m = m0 + rl;
            const float td = tdT[t * BATCH + m];
            const size_t o = (size_t)m * 512 + hcol;
            const float i_ = fsigm(acc[i][0][r] + bvi);
            const float f_ = fsigm(acc[i][1][r] + bvf);
            const float o_ = fsigm(acc[i][2][r] + bvo);
            const float ch = ftanh(acc[i][3][r] + bvc);
            const float tg = fsigm(tgs[rl * 17 + lr] + fsigm(td * wtt) + bt_);
            const float cn = f_ * c_reg[i][r] + (i_ + tg) * ch;
            c_reg[i][r] = cn;
            hcur[o] = (bf16)(o_ * ftanh(cn));
          }
        }
      }
    }
    __threadfence();
    grid.sync();

    // ================= phase B: gemm2 (hcur @ [Wb|Wg] + baPad -> hWbG bf16) ===
    {
      floatx4 acc2[2][2];
#pragma unroll
      for (int i = 0; i < 2; ++i)
#pragma unroll
        for (int j = 0; j < 2; ++j) {
          acc2[i][j][0] = 0.f; acc2[i][j][1] = 0.f; acc2[i][j][2] = 0.f; acc2[i][j][3] = 0.f;
        }
      for (int kt = 0; kt < 8; ++kt) {
        const int kb = kt * 64;
        __syncthreads();
#pragma unroll
        for (int s = 0; s < 2; ++s) {  // A: 8 groups of 8 rows, 2 per wave
          const int g = wv * 2 + s;
          const int r = g * 8 + g8;
          const bf16* src = hcur + (size_t)(m0b + r) * 512 + kb + cl * 8;
          __builtin_amdgcn_global_load_lds((gvoid*)src, (svoid*)&As[g * 512], 16, 0, 0);
        }
#pragma unroll
        for (int s = 0; s < 2; ++s) {  // B: 8 groups of 8 rows, 2 per wave
          const int g = wv * 2 + s;
          const int r = g * 8 + g8;
          const bf16* src = wbwgT + (size_t)(n0b + r) * 512 + kb + cl * 8;
          __builtin_amdgcn_global_load_lds((gvoid*)src, (svoid*)&Bs[g * 512], 16, 0, 0);
        }
        __syncthreads();
#pragma unroll
        for (int s = 0; s < 2; ++s) {
          const int lc = s * 4 + quad;
          bf16x8 afr[2];
          bf16x8 bfr[2];
#pragma unroll
          for (int i = 0; i < 2; ++i) {
            const int r = wy * 32 + i * 16 + lr;
            afr[i] = *reinterpret_cast<const bf16x8*>(&As[r * 64 + ((lc ^ (r & 7)) << 3)]);
          }
#pragma unroll
          for (int j = 0; j < 2; ++j) {
            const int r = wx * 32 + j * 16 + lr;
            bfr[j] = *reinterpret_cast<const bf16x8*>(&Bs[r * 64 + ((lc ^ (r & 7)) << 3)]);
          }
#pragma unroll
          for (int i = 0; i < 2; ++i)
#pragma unroll
            for (int j = 0; j < 2; ++j)
              acc2[i][j] =
                  __builtin_amdgcn_mfma_f32_16x16x32_bf16(afr[i], bfr[j], acc2[i][j], 0, 0, 0);
        }
      }
#pragma unroll
      for (int i = 0; i < 2; ++i) {
#pragma unroll
        for (int j = 0; j < 2; ++j) {
          const int n = n0b + wx * 32 + j * 16 + lr;
          const float bb = baPad[n];
#pragma unroll
          for (int r = 0; r < 4; ++r) {
            const int m = m0b + wy * 32 + i * 16 + quad * 4 + r;
            hWbG[(size_t)m * 1024 + n] = (bf16)(acc2[i][j][r] + bb);
          }
        }
      }
    }
    __threadfence();
    grid.sync();

    // ================= phase C: attention + h_new =================
    {
      const int b = bid * 4 + wv;
      const int k = t;
      float wb[8], sw_[8], vv[8];
      const bf16* wbp = hWbG + (size_t)b * 1024 + lane * 8;
      bf16x8 wbv = *reinterpret_cast<const bf16x8*>(wbp);
#pragma unroll
      for (int i = 0; i < 8; ++i) {
        wb[i] = (float)wbv[i];
        sw_[i] = sWa[lane * 8 + i];
        vv[i] = va[lane * 8 + i];
      }
      float pp = 0.f;
#pragma unroll
      for (int i = 0; i < 8; ++i) pp += vv[i] * ftanh(sw_[i] + wb[i]);
      float e_init = waveAllSum(pp);

      float e[15];
#pragma unroll
      for (int j = 0; j < 15; ++j) {
        if (j < k) {
          bf16x8 hv = *reinterpret_cast<const bf16x8*>(
              histWa + ((size_t)j * BATCH + b) * HDIM + lane * 8);
          float q = 0.f;
#pragma unroll
          for (int i = 0; i < 8; ++i) q += vv[i] * ftanh((float)hv[i] + wb[i]);
          e[j] = waveAllSum(q);
        }
      }
      float mx = (k < 15) ? e_init : -1e30f;
#pragma unroll
      for (int j = 0; j < 15; ++j)
        if (j < k) mx = fmaxf(mx, e[j]);
      float winit = (k < 15) ? (float)(15 - k) * __expf(e_init - mx) : 0.f;
      float denom = winit;
      float w[15];
#pragma unroll
      for (int j = 0; j < 15; ++j)
        if (j < k) { w[j] = __expf(e[j] - mx); denom += w[j]; }
      float inv = 1.f / denom;
      float cx[8];
      float ai = winit * inv;
#pragma unroll
      for (int i = 0; i < 8; ++i) cx[i] = ai * sWe[lane * 8 + i];
#pragma unroll
      for (int j = 0; j < 15; ++j) {
        if (j < k) {
          bf16x8 hv = *reinterpret_cast<const bf16x8*>(
              histWe + ((size_t)j * BATCH + b) * HDIM + lane * 8);
          float aj = w[j] * inv;
#pragma unroll
          for (int i = 0; i < 8; ++i) cx[i] += aj * (float)hv[i];
        }
      }
      bf16x8 wgv = *reinterpret_cast<const bf16x8*>(wbp + 512);
      bf16x8 hnew;
#pragma unroll
      for (int i = 0; i < 8; ++i)
        hnew[i] = (bf16)ftanh(cx[i] + (float)wgv[i] + bh[lane * 8 + i]);
      *reinterpret_cast<bf16x8*>(hbuf + (size_t)b * HDIM + lane * 8) = hnew;
    }
    __threadfence();
    grid.sync();
  }
}

// ---------------------------------------------------------------------------
// Fallback-path kernels (R8 structure) + head GEMMs. gemm1_fused only used if
// the cooperative launch fails (e.g., capture restriction).
// ---------------------------------------------------------------------------
__global__ __launch_bounds__(256, 4)
void gemm1_fused(const bf16* __restrict__ A1, const bf16* __restrict__ A2,
                 const bf16* __restrict__ BT,
                 const float* __restrict__ tdT, const float* __restrict__ bvec,
                 const float* __restrict__ WtT, const float* __restrict__ bT,
                 float* __restrict__ cbuf, bf16* __restrict__ hcur,
                 bf16* __restrict__ waSlot, bf16* __restrict__ weSlot) {
  constexpr int BM = 128, BN = 128, BK = 64;
  constexpr int TM = 4, TN = 4;
  __shared__ __align__(16) bf16 As[BM * BK];
  __shared__ __align__(16) bf16 Bs[BN * BK];

  const int tid = threadIdx.x;
  const int lane = tid & 63;
  const int wv = tid >> 6;
  const int wy = wv >> 1;
  const int wx = wv & 1;
  const int quad = lane >> 4;
  const int lr = lane & 15;
  const int bid = blockIdx.x;
  const int xcd = bid & 7;
  const int p = bid >> 3;
  const int n_idx = (xcd << 2) | (p >> 5);
  const int m_idx = p & 31;
  const int m0 = m_idx * BM;
  const int n0 = n_idx * BN;
  const int g8 = lane >> 3;
  const int cl = (lane & 7) ^ g8;

  floatx4 acc[TM][TN];
#pragma unroll
  for (int i = 0; i < TM; ++i)
#pragma unroll
    for (int j = 0; j < TN; ++j) {
      acc[i][j][0] = 0.f; acc[i][j][1] = 0.f; acc[i][j][2] = 0.f; acc[i][j][3] = 0.f;
    }

  for (int kt = 0; kt < KA / BK; ++kt) {
    const int kb = kt * BK;
    __syncthreads();
#pragma unroll
    for (int s = 0; s < 4; ++s) {
      const int g = wv * 4 + s;
      const int r = g * 8 + g8;
      const int col = kb + cl * 8;
      const bf16* src = (kt == 0) ? (A1 + (size_t)(m0 + r) * 64 + col)
                                  : (A2 + (size_t)(m0 + r) * 512 + (col - 64));
      __builtin_amdgcn_global_load_lds((gvoid*)src, (svoid*)&As[g * 512], 16, 0, 0);
    }
#pragma unroll
    for (int s = 0; s < 4; ++s) {
      const int g = wv * 4 + s;
      const int r = g * 8 + g8;
      const bf16* src = BT + (size_t)(n0 + r) * KA + kb + cl * 8;
      __builtin_amdgcn_global_load_lds((gvoid*)src, (svoid*)&Bs[g * 512], 16, 0, 0);
    }
    __syncthreads();
#pragma unroll
    for (int s = 0; s < 2; ++s) {
      const int lc = s * 4 + quad;
      bf16x8 afr[TM];
      bf16x8 bfr[TN];
#pragma unroll
      for (int i = 0; i < TM; ++i) {
        const int r = wy * 64 + i * 16 + lr;
        afr[i] = *reinterpret_cast<const bf16x8*>(&As[r * 64 + ((lc ^ (r & 7)) << 3)]);
      }
#pragma unroll
      for (int j = 0; j < TN; ++j) {
        const int r = wx * 64 + j * 16 + lr;
        bfr[j] = *reinterpret_cast<const bf16x8*>(&Bs[r * 64 + ((lc ^ (r & 7)) << 3)]);
      }
#pragma unroll
      for (int i = 0; i < TM; ++i)
#pragma unroll
        for (int j = 0; j < TN; ++j)
          acc[i][j] = __builtin_amdgcn_mfma_f32_16x16x32_bf16(afr[i], bfr[j], acc[i][j], 0, 0, 0);
    }
  }

  __syncthreads();
  float* tgs = reinterpret_cast<float*>(As);
  const int hcol = (n0 >> 7) * 16 + lr;
  if (wx == 1) {
#pragma unroll
    for (int i = 0; i < TM; ++i) {
#pragma unroll
      for (int r = 0; r < 4; ++r) {
        const int rl = wy * 64 + i * 16 + quad * 4 + r;
        const int m = m0 + rl;
        const size_t o = (size_t)m * 512 + hcol;
        tgs[rl * 17 + lr] = acc[i][0][r];
        waSlot[o] = (bf16)acc[i][1][r];
        weSlot[o] = (bf16)acc[i][2][r];
      }
    }
  }
  __syncthreads();
  if (wx == 0) {
    const float bvi = bvec[hcol], bvf = bvec[512 + hcol];
    const float bvo = bvec[1024 + hcol], bvc = bvec[1536 + hcol];
    const float wtt = WtT[hcol], bt_ = bT[hcol];
#pragma unroll
    for (int i = 0; i < TM; ++i) {
#pragma unroll
      for (int r = 0; r < 4; ++r) {
        const int rl = wy * 64 + i * 16 + quad * 4 + r;
        const int m = m0 + rl;
        const float td = tdT[m];
        const size_t o = (size_t)m * 512 + hcol;
        const float c_old = cbuf[o];
        const float i_ = fsigm(acc[i][0][r] + bvi);
        const float f_ = fsigm(acc[i][1][r] + bvf);
        const float o_ = fsigm(acc[i][2][r] + bvo);
        const float ch = ftanh(acc[i][3][r] + bvc);
        const float tg = fsigm(tgs[rl * 17 + lr] + fsigm(td * wtt) + bt_);
        const float cn = f_ * c_old + (i_ + tg) * ch;
        cbuf[o] = cn;
        hcur[o] = (bf16)(o_ * ftanh(cn));
      }
    }
  }
}

template <int BM, int BN>
__global__ __launch_bounds__(256)
void gemm_glds_kernel(const bf16* __restrict__ A1, int ld1, int K1,
                      const bf16* __restrict__ A2, int ld2,
                      const bf16* __restrict__ BT, int K, int mode,
                      float* __restrict__ outF, int ldF, const float* __restrict__ colBias,
                      bf16* __restrict__ outBa, int ldBa, const float* __restrict__ cBias2) {
  constexpr int BK = 32;
  constexpr int WM = BM / 2;
  constexpr int WN = BN / 2;
  constexpr int TM = WM / 16;
  constexpr int TN = WN / 16;
  constexpr int AIW = BM / 64;
  constexpr int BIW = BN / 64;
  __shared__ __align__(16) bf16 As[BM * BK];
  __shared__ __align__(16) bf16 Bs[BN * BK];

  const int tid = threadIdx.x;
  const int lane = tid & 63;
  const int wv = tid >> 6;
  const int wy = wv >> 1;
  const int wx = wv & 1;
  const int quad = lane >> 4;
  const int lr = lane & 15;
  const int m0 = blockIdx.y * BM;
  const int n0 = blockIdx.x * BN;
  const int sw = quad ^ ((lr >> 1) & 3);
  const int srow = lane >> 2;
  const int cl = (lane & 3) ^ ((lane >> 3) & 3);

  floatx4 acc[TM][TN];
#pragma unroll
  for (int i = 0; i < TM; ++i)
#pragma unroll
    for (int j = 0; j < TN; ++j) {
      acc[i][j][0] = 0.f; acc[i][j][1] = 0.f; acc[i][j][2] = 0.f; acc[i][j][3] = 0.f;
    }

  const int kTiles = K / BK;
  for (int kt = 0; kt < kTiles; ++kt) {
    const int kb = kt * BK;
    __syncthreads();
#pragma unroll
    for (int s = 0; s < AIW; ++s) {
      const int rbase = (wv * AIW + s) * 16;
      const int r = rbase + srow;
      const int col = kb + cl * 8;
      const bf16* src = (col < K1) ? (A1 + (size_t)(m0 + r) * ld1 + col)
                                   : (A2 + (size_t)(m0 + r) * ld2 + (col - K1));
      __builtin_amdgcn_global_load_lds((gvoid*)src, (svoid*)&As[rbase * BK], 16, 0, 0);
    }
#pragma unroll
    for (int s = 0; s < BIW; ++s) {
      const int rbase = (wv * BIW + s) * 16;
      const int r = rbase + srow;
      const bf16* src = BT + (size_t)(n0 + r) * K + kb + cl * 8;
      __builtin_amdgcn_global_load_lds((gvoid*)src, (svoid*)&Bs[rbase * BK], 16, 0, 0);
    }
    __syncthreads();
    bf16x8 afr[TM];
    bf16x8 bfr[TN];
#pragma unroll
    for (int i = 0; i < TM; ++i)
      afr[i] = *reinterpret_cast<const bf16x8*>(&As[(wy * WM + i * 16 + lr) * BK + sw * 8]);
#pragma unroll
    for (int j = 0; j < TN; ++j)
      bfr[j] = *reinterpret_cast<const bf16x8*>(&Bs[(wx * WN + j * 16 + lr) * BK + sw * 8]);
#pragma unroll
    for (int i = 0; i < TM; ++i)
#pragma unroll
      for (int j = 0; j < TN; ++j)
        acc[i][j] = __builtin_amdgcn_mfma_f32_16x16x32_bf16(afr[i], bfr[j], acc[i][j], 0, 0, 0);
  }

#pragma unroll
  for (int i = 0; i < TM; ++i) {
#pragma unroll
    for (int j = 0; j < TN; ++j) {
#pragma unroll
      for (int r = 0; r < 4; ++r) {
        int m = m0 + wy * WM + i * 16 + quad * 4 + r;
        int n = n0 + wx * WN + j * 16 + lr;
        float v = acc[i][j][r];
        if (mode == 0) {
          if (colBias != nullptr) v += colBias[n];
          outF[(size_t)m * ldF + n] = v;
        } else if (mode == 4) {
          v += colBias[n];
          outBa[(size_t)m * ldBa + n] = (bf16)v;
        } else {  // mode 3
          v += cBias2[n];
          v = v > 0.f ? v : 0.f;
          outBa[(size_t)m * ldBa + n] = (bf16)v;
        }
      }
    }
  }
}

// ---------------------------------------------------------------------------
// Setup kernels
// ---------------------------------------------------------------------------
__global__ void pack_wcombT_kernel(const float* __restrict__ Wx, const float* __restrict__ Uh,
                                   const float* __restrict__ Wt, const float* __restrict__ WxT,
                                   const float* __restrict__ Wa, const float* __restrict__ We,
                                   bf16* __restrict__ out) {
  int idx = blockIdx.x * 256 + threadIdx.x;
  if (idx >= NR * KA) return;
  int n = idx / KA;
  int k = idx - n * KA;
  int h = (n >> 7) * 16 + (n & 15);
  int role = (n >> 4) & 7;
  float v = 0.f;
  if (k < 63) {
    if (role < 4) v = Wx[k * 2048 + role * 512 + h];
    else if (role == 4) v = WxT[k * 512 + h];
  } else if (k == 63) {
    if (role < 3) v = Wt[role * 512 + h];
  } else {
    int kh = k - 64;
    if (role < 4) v = Uh[kh * 2048 + role * 512 + h];
    else if (role == 5) v = Wa[kh * 512 + h];
    else if (role == 6) v = We[kh * 512 + h];
  }
  out[idx] = (bf16)v;
}

__global__ void pack_t_kernel(const float* __restrict__ in, bf16* __restrict__ out, int N, int K) {
  int idx = blockIdx.x * 256 + threadIdx.x;
  if (idx >= N * K) return;
  int n = idx / K;
  int j = idx - n * K;
  out[idx] = (bf16)in[(size_t)j * N + n];
}

__global__ __launch_bounds__(512)
void setup_misc_kernel(const float* __restrict__ init_proj, const float* __restrict__ Wa,
                       const float* __restrict__ We, const float* __restrict__ ba,
                       float* __restrict__ sWa, float* __restrict__ sWe,
                       float* __restrict__ baPad) {
  __shared__ float s_sh[HDIM];
  int h = threadIdx.x;
  float acc = 0.f;
  for (int f = 0; f < 64; ++f) acc += init_proj[f * HDIM + h];
  s_sh[h] = acc;
  baPad[h] = ba[h];
  baPad[HDIM + h] = 0.f;
  __syncthreads();
  float a2 = 0.f, a3 = 0.f;
  for (int i = 0; i < HDIM; ++i) {
    a2 += s_sh[i] * Wa[i * HDIM + h];
    a3 += s_sh[i] * We[i * HDIM + h];
  }
  sWa[h] = a2;
  sWe[h] = a3;
}

__global__ void zero_state_kernel(float* __restrict__ c, bf16* __restrict__ h) {
  int idx = blockIdx.x * 256 + threadIdx.x;
  if (idx >= BATCH * HDIM) return;
  c[idx] = 0.f;
  h[idx] = (bf16)0.f;
}

__global__ void build_x_kernel(const float* __restrict__ inputs, bf16* __restrict__ xbuf,
                               float* __restrict__ tdT) {
  int idx = blockIdx.x * 256 + threadIdx.x;
  if (idx >= TSTEPS * BATCH * 64) return;
  int c = idx & 63;
  int bt = idx >> 6;
  int t = bt >> 12;
  int b = bt & 4095;
  float v;
  if (c < 63) {
    v = inputs[(size_t)b * 1024 + t * 64 + 1 + c];
  } else {
    v = inputs[(size_t)b * 1024 + t * 64];
    tdT[t * BATCH + b] = v;
  }
  xbuf[idx] = (bf16)v;
}

// attention (fallback path)
__global__ __launch_bounds__(256)
void attention_kernel(const bf16* __restrict__ hWbG,
                      const float* __restrict__ sWa, const float* __restrict__ sWe,
                      const float* __restrict__ va, const float* __restrict__ bh,
                      const bf16* __restrict__ histWa, const bf16* __restrict__ histWe,
                      bf16* __restrict__ hbuf, int k) {
  int b = blockIdx.x * 4 + (threadIdx.x >> 6);
  int lane = threadIdx.x & 63;
  float wb[8], sw_[8], vv[8];
  const bf16* wbp = hWbG + (size_t)b * 1024 + lane * 8;
  bf16x8 wbv = *reinterpret_cast<const bf16x8*>(wbp);
#pragma unroll
  for (int i = 0; i < 8; ++i) {
    wb[i] = (float)wbv[i];
    sw_[i] = sWa[lane * 8 + i];
    vv[i] = va[lane * 8 + i];
  }
  float p = 0.f;
#pragma unroll
  for (int i = 0; i < 8; ++i) p += vv[i] * ftanh(sw_[i] + wb[i]);
  float e_init = waveAllSum(p);

  float e[15];
#pragma unroll
  for (int j = 0; j < 15; ++j) {
    if (j < k) {
      bf16x8 hv = *reinterpret_cast<const bf16x8*>(
          histWa + ((size_t)j * BATCH + b) * HDIM + lane * 8);
      float q = 0.f;
#pragma unroll
      for (int i = 0; i < 8; ++i) q += vv[i] * ftanh((float)hv[i] + wb[i]);
      e[j] = waveAllSum(q);
    }
  }
  float mx = (k < 15) ? e_init : -1e30f;
#pragma unroll
  for (int j = 0; j < 15; ++j)
    if (j < k) mx = fmaxf(mx, e[j]);
  float winit = (k < 15) ? (float)(15 - k) * __expf(e_init - mx) : 0.f;
  float denom = winit;
  float w[15];
#pragma unroll
  for (int j = 0; j < 15; ++j)
    if (j < k) { w[j] = __expf(e[j] - mx); denom += w[j]; }
  float inv = 1.f / denom;
  float cx[8];
  float ai = winit * inv;
#pragma unroll
  for (int i = 0; i < 8; ++i) cx[i] = ai * sWe[lane * 8 + i];
#pragma unroll
  for (int j = 0; j < 15; ++j) {
    if (j < k) {
      bf16x8 hv = *reinterpret_cast<const bf16x8*>(
          histWe + ((size_t)j * BATCH + b) * HDIM + lane * 8);
      float aj = w[j] * inv;
#pragma unroll
      for (int i = 0; i < 8; ++i) cx[i] += aj * (float)hv[i];
    }
  }
  bf16x8 wgv = *reinterpret_cast<const bf16x8*>(wbp + 512);
  bf16x8 hnew;
#pragma unroll
  for (int i = 0; i < 8; ++i)
    hnew[i] = (bf16)ftanh(cx[i] + (float)wgv[i] + bh[lane * 8 + i]);
  *reinterpret_cast<bf16x8*>(hbuf + (size_t)b * HDIM + lane * 8) = hnew;
}

__global__ __launch_bounds__(256)
void head_kernel(const bf16* __restrict__ hd1, const float* __restrict__ W2,
                 const float* __restrict__ b2, const float* __restrict__ W3,
                 const float* __restrict__ b3, float* __restrict__ out) {
  __shared__ float W2s[256 * 32];
  __shared__ float b2s[32];
  __shared__ float W3s[64];
  __shared__ float b3s[2];
  for (int i = threadIdx.x; i < 256 * 32; i += 256) W2s[i] = W2[i];
  if (threadIdx.x < 32) b2s[threadIdx.x] = b2[threadIdx.x];
  if (threadIdx.x < 64) W3s[threadIdx.x] = W3[threadIdx.x];
  if (threadIdx.x < 2) b3s[threadIdx.x] = b3[threadIdx.x];
  __syncthreads();
  int row = blockIdx.x * 256 + threadIdx.x;
  float acc[32];
#pragma unroll
  for (int j = 0; j < 32; ++j) acc[j] = b2s[j];
  const bf16* hp = hd1 + (size_t)row * 256;
  for (int i = 0; i < 256; ++i) {
    float hv = (float)hp[i];
#pragma unroll
    for (int j = 0; j < 32; ++j) acc[j] += hv * W2s[i * 32 + j];
  }
  float l0 = b3s[0], l1 = b3s[1];
#pragma unroll
  for (int j = 0; j < 32; ++j) {
    float r = fmaxf(acc[j], 0.f);
    l0 += r * W3s[j * 2];
    l1 += r * W3s[j * 2 + 1];
  }
  float m = fmaxf(l0, l1);
  float e0 = __expf(l0 - m), e1 = __expf(l1 - m);
  float inv = 1.f / (e0 + e1);
  out[(size_t)row * 2] = e0 * inv;
  out[(size_t)row * 2 + 1] = e1 * inv;
}

// ---------------------------------------------------------------------------
extern "C" void kernel_launch(void* const* d_in, const int* in_sizes, int n_in,
                              void* d_out, int out_size, void* d_ws, size_t ws_size,
                              hipStream_t stream) {
  const float* inputs    = (const float*)d_in[0];
  const float* init_proj = (const float*)d_in[1];
  const float* Wx  = (const float*)d_in[3];
  const float* Uh  = (const float*)d_in[4];
  const float* Wt  = (const float*)d_in[5];
  const float* bv  = (const float*)d_in[6];
  const float* WxT = (const float*)d_in[7];
  const float* WtT = (const float*)d_in[8];
  const float* bT  = (const float*)d_in[9];
  const float* Wa  = (const float*)d_in[10];
  const float* Wb  = (const float*)d_in[11];
  const float* va  = (const float*)d_in[12];
  const float* ba  = (const float*)d_in[13];
  const float* We  = (const float*)d_in[14];
  const float* Wg  = (const float*)d_in[15];
  const float* bh  = (const float*)d_in[16];
  const float* W1  = (const float*)d_in[17];
  const float* b1  = (const float*)d_in[18];
  const float* W2  = (const float*)d_in[19];
  const float* b2  = (const float*)d_in[20];
  const float* W3  = (const float*)d_in[21];
  const float* b3  = (const float*)d_in[22];
  float* out = (float*)d_out;

  char* wp = (char*)d_ws;
  auto carve = [&](size_t bytes) -> void* {
    void* p = (void*)wp;
    wp += (bytes + 255) & ~(size_t)255;
    return p;
  };
  bf16* wcombT = (bf16*)carve((size_t)NR * KA * 2);
  bf16* wbwgT  = (bf16*)carve((size_t)1024 * 512 * 2);
  bf16* w1T    = (bf16*)carve((size_t)256 * 512 * 2);
  float* sWa   = (float*)carve(512 * 4);
  float* sWe   = (float*)carve(512 * 4);
  float* baPad = (float*)carve(1024 * 4);
  bf16* xbuf   = (bf16*)carve((size_t)TSTEPS * BATCH * 64 * 2);
  float* tdT   = (float*)carve((size_t)TSTEPS * BATCH * 4);
  float* cbuf  = (float*)carve((size_t)BATCH * HDIM * 4);
  bf16* hbuf   = (bf16*)carve((size_t)BATCH * HDIM * 2);
  bf16* hcur   = (bf16*)carve((size_t)BATCH * HDIM * 2);
  bf16* hWbG   = (bf16*)carve((size_t)BATCH * 1024 * 2);
  bf16* histWa = (bf16*)carve((size_t)16 * BATCH * HDIM * 2);
  bf16* histWe = (bf16*)carve((size_t)16 * BATCH * HDIM * 2);
  bf16* hd1    = (bf16*)carve((size_t)BATCH * 256 * 2);

  // ---- setup ----
  build_x_kernel<<<(TSTEPS * BATCH * 64) / 256, 256, 0, stream>>>(inputs, xbuf, tdT);
  pack_wcombT_kernel<<<(NR * KA + 255) / 256, 256, 0, stream>>>(Wx, Uh, Wt, WxT, Wa, We, wcombT);
  pack_t_kernel<<<(512 * 512) / 256, 256, 0, stream>>>(Wb, wbwgT, 512, 512);
  pack_t_kernel<<<(512 * 512) / 256, 256, 0, stream>>>(Wg, wbwgT + (size_t)512 * 512, 512, 512);
  pack_t_kernel<<<(256 * 512) / 256, 256, 0, stream>>>(W1, w1T, 256, 512);
  setup_misc_kernel<<<1, 512, 0, stream>>>(init_proj, Wa, We, ba, sWa, sWe, baPad);
  zero_state_kernel<<<(BATCH * HDIM) / 256, 256, 0, stream>>>(cbuf, hbuf);

  // ---- recurrence: one cooperative persistent kernel ----
  {
    const bf16* a_xbuf = xbuf;       const float* a_tdT = tdT;
    const bf16* a_wcombT = wcombT;   const float* a_bv = bv;
    const float* a_WtT = WtT;        const float* a_bT = bT;
    bf16* a_hcur = hcur;             bf16* a_hbuf = hbuf;
    bf16* a_hWa = histWa;            bf16* a_hWe = histWe;
    const bf16* a_wbwgT = wbwgT;     const float* a_baPad = baPad;
    const float* a_sWa = sWa;        const float* a_sWe = sWe;
    const float* a_va = va;          const float* a_bh = bh;
    bf16* a_hWbG = hWbG;
    void* args[] = {(void*)&a_xbuf, (void*)&a_tdT, (void*)&a_wcombT, (void*)&a_bv,
                    (void*)&a_WtT, (void*)&a_bT, (void*)&a_hcur, (void*)&a_hbuf,
                    (void*)&a_hWa, (void*)&a_hWe, (void*)&a_wbwgT, (void*)&a_baPad,
                    (void*)&a_sWa, (void*)&a_sWe, (void*)&a_va, (void*)&a_bh,
                    (void*)&a_hWbG};
    hipError_t err = hipLaunchCooperativeKernel((const void*)persist_kernel, dim3(1024),
                                                dim3(256), args, 0, stream);
    if (err != hipSuccess) {
      // fallback: R8 3-kernel loop (same numerics; cbuf-based)
      for (int t = 0; t < TSTEPS; ++t) {
        bf16* waSlot = histWa + (size_t)((t + 15) & 15) * BATCH * HDIM;
        bf16* weSlot = histWe + (size_t)((t + 15) & 15) * BATCH * HDIM;
        gemm1_fused<<<1024, 256, 0, stream>>>(
            xbuf + (size_t)t * BATCH * 64, hbuf, wcombT, tdT + (size_t)t * BATCH, bv, WtT, bT,
            cbuf, hcur, waSlot, weSlot);
        gemm_glds_kernel<64, 128><<<dim3(1024 / 128, BATCH / 64), 256, 0, stream>>>(
            hcur, 512, 512, hcur, 512, wbwgT, 512, 4, nullptr, 0, baPad, hWbG, 1024, nullptr);
        attention_kernel<<<BATCH / 4, 256, 0, stream>>>(hWbG, sWa, sWe, va, bh, histWa, histWe,
                                                        hbuf, t);
      }
    }
  }

  // ---- head ----
  gemm_glds_kernel<64, 128><<<dim3(256 / 128, BATCH / 64), 256, 0, stream>>>(
      hbuf, 512, 512, hbuf, 512, w1T, 512, 3, nullptr, 0, nullptr, hd1, 256, b1);
  head_kernel<<<BATCH / 256, 256, 0, stream>>>(hd1, W2, b2, W3, b3, out);
}

// Round 10
// 1196.052 us; speedup vs baseline: 11.8180x; 11.8180x over previous
//
#include <hip/hip_runtime.h>
#include <hip/hip_bf16.h>

typedef __bf16 bf16;
typedef __attribute__((ext_vector_type(8))) __bf16 bf16x8;
typedef __attribute__((ext_vector_type(4))) float floatx4;

#define HDIM 512
#define BATCH 4096
#define TSTEPS 16
#define KA 576      // A width: 63 x-feats + td + 512 h
#define NR 4096     // GEMM1 out cols: role-interleaved, 8 roles x 512 h

typedef const __attribute__((address_space(1))) void gvoid;
typedef __attribute__((address_space(3))) void svoid;

__device__ __forceinline__ float ftanh(float x) {
  float xx = fminf(fmaxf(x, -15.f), 15.f);
  float t = __expf(2.f * xx);
  return (t - 1.f) / (t + 1.f);
}
__device__ __forceinline__ float fsigm(float x) { return 1.0f / (1.0f + __expf(-x)); }

__device__ __forceinline__ float waveAllSum(float v) {
#pragma unroll
  for (int off = 32; off > 0; off >>= 1) v += __shfl_xor(v, off, 64);
  return v;
}

// ---------------------------------------------------------------------------
// Fused GEMM1 + gates (R8 proven). BM=BN=128, BK=64, XOR-swizzled glds staging.
// ---------------------------------------------------------------------------
__global__ __launch_bounds__(256, 4)
void gemm1_fused(const bf16* __restrict__ A1, const bf16* __restrict__ A2,
                 const bf16* __restrict__ BT,
                 const float* __restrict__ tdT, const float* __restrict__ bvec,
                 const float* __restrict__ WtT, const float* __restrict__ bT,
                 float* __restrict__ cbuf, bf16* __restrict__ hcur,
                 bf16* __restrict__ waSlot, bf16* __restrict__ weSlot) {
  constexpr int BM = 128, BN = 128, BK = 64;
  constexpr int TM = 4, TN = 4;
  __shared__ __align__(16) bf16 As[BM * BK];  // 16 KB; aliased as tg exchange after K-loop
  __shared__ __align__(16) bf16 Bs[BN * BK];  // 16 KB

  const int tid = threadIdx.x;
  const int lane = tid & 63;
  const int wv = tid >> 6;
  const int wy = wv >> 1;
  const int wx = wv & 1;
  const int quad = lane >> 4;
  const int lr = lane & 15;
  const int bid = blockIdx.x;
  const int xcd = bid & 7;
  const int p = bid >> 3;
  const int n_idx = (xcd << 2) | (p >> 5);
  const int m_idx = p & 31;
  const int m0 = m_idx * BM;
  const int n0 = n_idx * BN;
  const int g8 = lane >> 3;
  const int cl = (lane & 7) ^ g8;  // logical chunk fetched (phys = lc ^ (row&7))

  floatx4 acc[TM][TN];
#pragma unroll
  for (int i = 0; i < TM; ++i)
#pragma unroll
    for (int j = 0; j < TN; ++j) {
      acc[i][j][0] = 0.f; acc[i][j][1] = 0.f; acc[i][j][2] = 0.f; acc[i][j][3] = 0.f;
    }

  for (int kt = 0; kt < KA / BK; ++kt) {
    const int kb = kt * BK;
    __syncthreads();
#pragma unroll
    for (int s = 0; s < 4; ++s) {
      const int g = wv * 4 + s;
      const int r = g * 8 + g8;
      const int col = kb + cl * 8;
      const bf16* src = (kt == 0) ? (A1 + (size_t)(m0 + r) * 64 + col)
                                  : (A2 + (size_t)(m0 + r) * 512 + (col - 64));
      __builtin_amdgcn_global_load_lds((gvoid*)src, (svoid*)&As[g * 512], 16, 0, 0);
    }
#pragma unroll
    for (int s = 0; s < 4; ++s) {
      const int g = wv * 4 + s;
      const int r = g * 8 + g8;
      const bf16* src = BT + (size_t)(n0 + r) * KA + kb + cl * 8;
      __builtin_amdgcn_global_load_lds((gvoid*)src, (svoid*)&Bs[g * 512], 16, 0, 0);
    }
    __syncthreads();
#pragma unroll
    for (int s = 0; s < 2; ++s) {
      const int lc = s * 4 + quad;
      bf16x8 afr[TM];
      bf16x8 bfr[TN];
#pragma unroll
      for (int i = 0; i < TM; ++i) {
        const int r = wy * 64 + i * 16 + lr;
        afr[i] = *reinterpret_cast<const bf16x8*>(&As[r * 64 + ((lc ^ (r & 7)) << 3)]);
      }
#pragma unroll
      for (int j = 0; j < TN; ++j) {
        const int r = wx * 64 + j * 16 + lr;
        bfr[j] = *reinterpret_cast<const bf16x8*>(&Bs[r * 64 + ((lc ^ (r & 7)) << 3)]);
      }
#pragma unroll
      for (int i = 0; i < TM; ++i)
#pragma unroll
        for (int j = 0; j < TN; ++j)
          acc[i][j] = __builtin_amdgcn_mfma_f32_16x16x32_bf16(afr[i], bfr[j], acc[i][j], 0, 0, 0);
    }
  }

  __syncthreads();
  float* tgs = reinterpret_cast<float*>(As);  // 128*17*4 = 8704 B
  const int hcol = (n0 >> 7) * 16 + lr;
  if (wx == 1) {
#pragma unroll
    for (int i = 0; i < TM; ++i) {
#pragma unroll
      for (int r = 0; r < 4; ++r) {
        const int rl = wy * 64 + i * 16 + quad * 4 + r;
        const int m = m0 + rl;
        const size_t o = (size_t)m * 512 + hcol;
        tgs[rl * 17 + lr] = acc[i][0][r];
        waSlot[o] = (bf16)acc[i][1][r];
        weSlot[o] = (bf16)acc[i][2][r];
      }
    }
  }
  __syncthreads();
  if (wx == 0) {
    const float bvi = bvec[hcol], bvf = bvec[512 + hcol];
    const float bvo = bvec[1024 + hcol], bvc = bvec[1536 + hcol];
    const float wtt = WtT[hcol], bt_ = bT[hcol];
#pragma unroll
    for (int i = 0; i < TM; ++i) {
#pragma unroll
      for (int r = 0; r < 4; ++r) {
        const int rl = wy * 64 + i * 16 + quad * 4 + r;
        const int m = m0 + rl;
        const float td = tdT[m];
        const size_t o = (size_t)m * 512 + hcol;
        const float c_old = cbuf[o];
        const float i_ = fsigm(acc[i][0][r] + bvi);
        const float f_ = fsigm(acc[i][1][r] + bvf);
        const float o_ = fsigm(acc[i][2][r] + bvo);
        const float ch = ftanh(acc[i][3][r] + bvc);
        const float tg = fsigm(tgs[rl * 17 + lr] + fsigm(td * wtt) + bt_);
        const float cn = f_ * c_old + (i_ + tg) * ch;
        cbuf[o] = cn;
        hcur[o] = (bf16)(o_ * ftanh(cn));
      }
    }
  }
}

// ---------------------------------------------------------------------------
// GEMM2: hcur[4096x512] @ wbwgT^T -> hWbG bf16 [4096x1024] (+baPad).
// 1024 blocks of 64x64 tiles (64 m-tiles x 16 n-tiles), BK=64, 4 blocks/CU.
// Same XOR-swizzled glds staging as gemm1 (proven conflict-free).
// ---------------------------------------------------------------------------
__global__ __launch_bounds__(256, 4)
void gemm2_kernel(const bf16* __restrict__ hcur, const bf16* __restrict__ wbwgT,
                  const float* __restrict__ baPad, bf16* __restrict__ hWbG) {
  __shared__ __align__(16) bf16 As[64 * 64];  // 8 KB
  __shared__ __align__(16) bf16 Bs[64 * 64];  // 8 KB

  const int tid = threadIdx.x;
  const int lane = tid & 63;
  const int wv = tid >> 6;
  const int wy = wv >> 1;
  const int wx = wv & 1;
  const int quad = lane >> 4;
  const int lr = lane & 15;
  const int bid = blockIdx.x;
  const int m0 = (bid >> 4) * 64;
  const int n0 = (bid & 15) * 64;
  const int g8 = lane >> 3;
  const int cl = (lane & 7) ^ g8;

  floatx4 acc[2][2];
#pragma unroll
  for (int i = 0; i < 2; ++i)
#pragma unroll
    for (int j = 0; j < 2; ++j) {
      acc[i][j][0] = 0.f; acc[i][j][1] = 0.f; acc[i][j][2] = 0.f; acc[i][j][3] = 0.f;
    }

  for (int kt = 0; kt < 8; ++kt) {
    const int kb = kt * 64;
    __syncthreads();
#pragma unroll
    for (int s = 0; s < 2; ++s) {  // A: 8 groups of 8 rows, 2 per wave
      const int g = wv * 2 + s;
      const int r = g * 8 + g8;
      const bf16* src = hcur + (size_t)(m0 + r) * 512 + kb + cl * 8;
      __builtin_amdgcn_global_load_lds((gvoid*)src, (svoid*)&As[g * 512], 16, 0, 0);
    }
#pragma unroll
    for (int s = 0; s < 2; ++s) {  // B: 8 groups of 8 rows, 2 per wave
      const int g = wv * 2 + s;
      const int r = g * 8 + g8;
      const bf16* src = wbwgT + (size_t)(n0 + r) * 512 + kb + cl * 8;
      __builtin_amdgcn_global_load_lds((gvoid*)src, (svoid*)&Bs[g * 512], 16, 0, 0);
    }
    __syncthreads();
#pragma unroll
    for (int s = 0; s < 2; ++s) {
      const int lc = s * 4 + quad;
      bf16x8 afr[2];
      bf16x8 bfr[2];
#pragma unroll
      for (int i = 0; i < 2; ++i) {
        const int r = wy * 32 + i * 16 + lr;
        afr[i] = *reinterpret_cast<const bf16x8*>(&As[r * 64 + ((lc ^ (r & 7)) << 3)]);
      }
#pragma unroll
      for (int j = 0; j < 2; ++j) {
        const int r = wx * 32 + j * 16 + lr;
        bfr[j] = *reinterpret_cast<const bf16x8*>(&Bs[r * 64 + ((lc ^ (r & 7)) << 3)]);
      }
#pragma unroll
      for (int i = 0; i < 2; ++i)
#pragma unroll
        for (int j = 0; j < 2; ++j)
          acc[i][j] = __builtin_amdgcn_mfma_f32_16x16x32_bf16(afr[i], bfr[j], acc[i][j], 0, 0, 0);
    }
  }

#pragma unroll
  for (int i = 0; i < 2; ++i) {
#pragma unroll
    for (int j = 0; j < 2; ++j) {
      const int n = n0 + wx * 32 + j * 16 + lr;
      const float bb = baPad[n];
#pragma unroll
      for (int r = 0; r < 4; ++r) {
        const int m = m0 + wy * 32 + i * 16 + quad * 4 + r;
        hWbG[(size_t)m * 1024 + n] = (bf16)(acc[i][j][r] + bb);
      }
    }
  }
}

// ---------------------------------------------------------------------------
// Generic MFMA GEMM (glds staging, BK=32 swizzle) — head only.
// mode 3: relu(v+cBias2) -> bf16 outBa
// ---------------------------------------------------------------------------
template <int BM, int BN>
__global__ __launch_bounds__(256)
void gemm_glds_kernel(const bf16* __restrict__ A1, int ld1, int K1,
                      const bf16* __restrict__ A2, int ld2,
                      const bf16* __restrict__ BT, int K, int mode,
                      float* __restrict__ outF, int ldF, const float* __restrict__ colBias,
                      bf16* __restrict__ outBa, int ldBa, const float* __restrict__ cBias2) {
  constexpr int BK = 32;
  constexpr int WM = BM / 2;
  constexpr int WN = BN / 2;
  constexpr int TM = WM / 16;
  constexpr int TN = WN / 16;
  constexpr int AIW = BM / 64;
  constexpr int BIW = BN / 64;
  __shared__ __align__(16) bf16 As[BM * BK];
  __shared__ __align__(16) bf16 Bs[BN * BK];

  const int tid = threadIdx.x;
  const int lane = tid & 63;
  const int wv = tid >> 6;
  const int wy = wv >> 1;
  const int wx = wv & 1;
  const int quad = lane >> 4;
  const int lr = lane & 15;
  const int m0 = blockIdx.y * BM;
  const int n0 = blockIdx.x * BN;
  const int sw = quad ^ ((lr >> 1) & 3);
  const int srow = lane >> 2;
  const int cl = (lane & 3) ^ ((lane >> 3) & 3);

  floatx4 acc[TM][TN];
#pragma unroll
  for (int i = 0; i < TM; ++i)
#pragma unroll
    for (int j = 0; j < TN; ++j) {
      acc[i][j][0] = 0.f; acc[i][j][1] = 0.f; acc[i][j][2] = 0.f; acc[i][j][3] = 0.f;
    }

  const int kTiles = K / BK;
  for (int kt = 0; kt < kTiles; ++kt) {
    const int kb = kt * BK;
    __syncthreads();
#pragma unroll
    for (int s = 0; s < AIW; ++s) {
      const int rbase = (wv * AIW + s) * 16;
      const int r = rbase + srow;
      const int col = kb + cl * 8;
      const bf16* src = (col < K1) ? (A1 + (size_t)(m0 + r) * ld1 + col)
                                   : (A2 + (size_t)(m0 + r) * ld2 + (col - K1));
      __builtin_amdgcn_global_load_lds((gvoid*)src, (svoid*)&As[rbase * BK], 16, 0, 0);
    }
#pragma unroll
    for (int s = 0; s < BIW; ++s) {
      const int rbase = (wv * BIW + s) * 16;
      const int r = rbase + srow;
      const bf16* src = BT + (size_t)(n0 + r) * K + kb + cl * 8;
      __builtin_amdgcn_global_load_lds((gvoid*)src, (svoid*)&Bs[rbase * BK], 16, 0, 0);
    }
    __syncthreads();
    bf16x8 afr[TM];
    bf16x8 bfr[TN];
#pragma unroll
    for (int i = 0; i < TM; ++i)
      afr[i] = *reinterpret_cast<const bf16x8*>(&As[(wy * WM + i * 16 + lr) * BK + sw * 8]);
#pragma unroll
    for (int j = 0; j < TN; ++j)
      bfr[j] = *reinterpret_cast<const bf16x8*>(&Bs[(wx * WN + j * 16 + lr) * BK + sw * 8]);
#pragma unroll
    for (int i = 0; i < TM; ++i)
#pragma unroll
      for (int j = 0; j < TN; ++j)
        acc[i][j] = __builtin_amdgcn_mfma_f32_16x16x32_bf16(afr[i], bfr[j], acc[i][j], 0, 0, 0);
  }

#pragma unroll
  for (int i = 0; i < TM; ++i) {
#pragma unroll
    for (int j = 0; j < TN; ++j) {
#pragma unroll
      for (int r = 0; r < 4; ++r) {
        int m = m0 + wy * WM + i * 16 + quad * 4 + r;
        int n = n0 + wx * WN + j * 16 + lr;
        float v = acc[i][j][r];
        if (mode == 0) {
          if (colBias != nullptr) v += colBias[n];
          outF[(size_t)m * ldF + n] = v;
        } else {  // mode 3
          v += cBias2[n];
          v = v > 0.f ? v : 0.f;
          outBa[(size_t)m * ldBa + n] = (bf16)v;
        }
      }
    }
  }
}

// ---------------------------------------------------------------------------
// Setup kernels (run every call; ws re-poisoned by harness)
// ---------------------------------------------------------------------------
__global__ void pack_wcombT_kernel(const float* __restrict__ Wx, const float* __restrict__ Uh,
                                   const float* __restrict__ Wt, const float* __restrict__ WxT,
                                   const float* __restrict__ Wa, const float* __restrict__ We,
                                   bf16* __restrict__ out) {
  int idx = blockIdx.x * 256 + threadIdx.x;
  if (idx >= NR * KA) return;
  int n = idx / KA;
  int k = idx - n * KA;
  int h = (n >> 7) * 16 + (n & 15);
  int role = (n >> 4) & 7;
  float v = 0.f;
  if (k < 63) {
    if (role < 4) v = Wx[k * 2048 + role * 512 + h];
    else if (role == 4) v = WxT[k * 512 + h];
  } else if (k == 63) {
    if (role < 3) v = Wt[role * 512 + h];
  } else {
    int kh = k - 64;
    if (role < 4) v = Uh[kh * 2048 + role * 512 + h];
    else if (role == 5) v = Wa[kh * 512 + h];
    else if (role == 6) v = We[kh * 512 + h];
  }
  out[idx] = (bf16)v;
}

__global__ void pack_t_kernel(const float* __restrict__ in, bf16* __restrict__ out, int N, int K) {
  int idx = blockIdx.x * 256 + threadIdx.x;
  if (idx >= N * K) return;
  int n = idx / K;
  int j = idx - n * K;
  out[idx] = (bf16)in[(size_t)j * N + n];
}

__global__ __launch_bounds__(512)
void setup_misc_kernel(const float* __restrict__ init_proj, const float* __restrict__ Wa,
                       const float* __restrict__ We, const float* __restrict__ ba,
                       float* __restrict__ sWa, float* __restrict__ sWe,
                       float* __restrict__ baPad) {
  __shared__ float s_sh[HDIM];
  int h = threadIdx.x;
  float acc = 0.f;
  for (int f = 0; f < 64; ++f) acc += init_proj[f * HDIM + h];
  s_sh[h] = acc;
  baPad[h] = ba[h];
  baPad[HDIM + h] = 0.f;
  __syncthreads();
  float a2 = 0.f, a3 = 0.f;
  for (int i = 0; i < HDIM; ++i) {
    a2 += s_sh[i] * Wa[i * HDIM + h];
    a3 += s_sh[i] * We[i * HDIM + h];
  }
  sWa[h] = a2;
  sWe[h] = a3;
}

__global__ void zero_state_kernel(float* __restrict__ c, bf16* __restrict__ h) {
  int idx = blockIdx.x * 256 + threadIdx.x;
  if (idx >= BATCH * HDIM) return;
  c[idx] = 0.f;
  h[idx] = (bf16)0.f;
}

__global__ void build_x_kernel(const float* __restrict__ inputs, bf16* __restrict__ xbuf,
                               float* __restrict__ tdT) {
  int idx = blockIdx.x * 256 + threadIdx.x;
  if (idx >= TSTEPS * BATCH * 64) return;
  int c = idx & 63;
  int bt = idx >> 6;
  int t = bt >> 12;
  int b = bt & 4095;
  float v;
  if (c < 63) {
    v = inputs[(size_t)b * 1024 + t * 64 + 1 + c];
  } else {
    v = inputs[(size_t)b * 1024 + t * 64];
    tdT[t * BATCH + b] = v;
  }
  xbuf[idx] = (bf16)v;
}

// attention + h_new epilogue; 4 waves/block, one batch row per wave
__global__ __launch_bounds__(256)
void attention_kernel(const bf16* __restrict__ hWbG,
                      const float* __restrict__ sWa, const float* __restrict__ sWe,
                      const float* __restrict__ va, const float* __restrict__ bh,
                      const bf16* __restrict__ histWa, const bf16* __restrict__ histWe,
                      bf16* __restrict__ hbuf, int k) {
  int b = blockIdx.x * 4 + (threadIdx.x >> 6);
  int lane = threadIdx.x & 63;
  float wb[8], sw_[8], vv[8];
  const bf16* wbp = hWbG + (size_t)b * 1024 + lane * 8;
  bf16x8 wbv = *reinterpret_cast<const bf16x8*>(wbp);
#pragma unroll
  for (int i = 0; i < 8; ++i) {
    wb[i] = (float)wbv[i];
    sw_[i] = sWa[lane * 8 + i];
    vv[i] = va[lane * 8 + i];
  }
  float p = 0.f;
#pragma unroll
  for (int i = 0; i < 8; ++i) p += vv[i] * ftanh(sw_[i] + wb[i]);
  float e_init = waveAllSum(p);

  float e[15];
#pragma unroll
  for (int j = 0; j < 15; ++j) {
    if (j < k) {
      bf16x8 hv = *reinterpret_cast<const bf16x8*>(
          histWa + ((size_t)j * BATCH + b) * HDIM + lane * 8);
      float q = 0.f;
#pragma unroll
      for (int i = 0; i < 8; ++i) q += vv[i] * ftanh((float)hv[i] + wb[i]);
      e[j] = waveAllSum(q);
    }
  }
  float mx = (k < 15) ? e_init : -1e30f;
#pragma unroll
  for (int j = 0; j < 15; ++j)
    if (j < k) mx = fmaxf(mx, e[j]);
  float winit = (k < 15) ? (float)(15 - k) * __expf(e_init - mx) : 0.f;
  float denom = winit;
  float w[15];
#pragma unroll
  for (int j = 0; j < 15; ++j)
    if (j < k) { w[j] = __expf(e[j] - mx); denom += w[j]; }
  float inv = 1.f / denom;
  float cx[8];
  float ai = winit * inv;
#pragma unroll
  for (int i = 0; i < 8; ++i) cx[i] = ai * sWe[lane * 8 + i];
#pragma unroll
  for (int j = 0; j < 15; ++j) {
    if (j < k) {
      bf16x8 hv = *reinterpret_cast<const bf16x8*>(
          histWe + ((size_t)j * BATCH + b) * HDIM + lane * 8);
      float aj = w[j] * inv;
#pragma unroll
      for (int i = 0; i < 8; ++i) cx[i] += aj * (float)hv[i];
    }
  }
  bf16x8 wgv = *reinterpret_cast<const bf16x8*>(wbp + 512);
  bf16x8 hnew;
#pragma unroll
  for (int i = 0; i < 8; ++i)
    hnew[i] = (bf16)ftanh(cx[i] + (float)wgv[i] + bh[lane * 8 + i]);
  *reinterpret_cast<bf16x8*>(hbuf + (size_t)b * HDIM + lane * 8) = hnew;
}

__global__ __launch_bounds__(256)
void head_kernel(const bf16* __restrict__ hd1, const float* __restrict__ W2,
                 const float* __restrict__ b2, const float* __restrict__ W3,
                 const float* __restrict__ b3, float* __restrict__ out) {
  __shared__ float W2s[256 * 32];
  __shared__ float b2s[32];
  __shared__ float W3s[64];
  __shared__ float b3s[2];
  for (int i = threadIdx.x; i < 256 * 32; i += 256) W2s[i] = W2[i];
  if (threadIdx.x < 32) b2s[threadIdx.x] = b2[threadIdx.x];
  if (threadIdx.x < 64) W3s[threadIdx.x] = W3[threadIdx.x];
  if (threadIdx.x < 2) b3s[threadIdx.x] = b3[threadIdx.x];
  __syncthreads();
  int row = blockIdx.x * 256 + threadIdx.x;
  float acc[32];
#pragma unroll
  for (int j = 0; j < 32; ++j) acc[j] = b2s[j];
  const bf16* hp = hd1 + (size_t)row * 256;
  for (int i = 0; i < 256; ++i) {
    float hv = (float)hp[i];
#pragma unroll
    for (int j = 0; j < 32; ++j) acc[j] += hv * W2s[i * 32 + j];
  }
  float l0 = b3s[0], l1 = b3s[1];
#pragma unroll
  for (int j = 0; j < 32; ++j) {
    float r = fmaxf(acc[j], 0.f);
    l0 += r * W3s[j * 2];
    l1 += r * W3s[j * 2 + 1];
  }
  float m = fmaxf(l0, l1);
  float e0 = __expf(l0 - m), e1 = __expf(l1 - m);
  float inv = 1.f / (e0 + e1);
  out[(size_t)row * 2] = e0 * inv;
  out[(size_t)row * 2 + 1] = e1 * inv;
}

// ---------------------------------------------------------------------------
extern "C" void kernel_launch(void* const* d_in, const int* in_sizes, int n_in,
                              void* d_out, int out_size, void* d_ws, size_t ws_size,
                              hipStream_t stream) {
  const float* inputs    = (const float*)d_in[0];
  const float* init_proj = (const float*)d_in[1];
  const float* Wx  = (const float*)d_in[3];
  const float* Uh  = (const float*)d_in[4];
  const float* Wt  = (const float*)d_in[5];
  const float* bv  = (const float*)d_in[6];
  const float* WxT = (const float*)d_in[7];
  const float* WtT = (const float*)d_in[8];
  const float* bT  = (const float*)d_in[9];
  const float* Wa  = (const float*)d_in[10];
  const float* Wb  = (const float*)d_in[11];
  const float* va  = (const float*)d_in[12];
  const float* ba  = (const float*)d_in[13];
  const float* We  = (const float*)d_in[14];
  const float* Wg  = (const float*)d_in[15];
  const float* bh  = (const float*)d_in[16];
  const float* W1  = (const float*)d_in[17];
  const float* b1  = (const float*)d_in[18];
  const float* W2  = (const float*)d_in[19];
  const float* b2  = (const float*)d_in[20];
  const float* W3  = (const float*)d_in[21];
  const float* b3  = (const float*)d_in[22];
  float* out = (float*)d_out;

  char* wp = (char*)d_ws;
  auto carve = [&](size_t bytes) -> void* {
    void* p = (void*)wp;
    wp += (bytes + 255) & ~(size_t)255;
    return p;
  };
  bf16* wcombT = (bf16*)carve((size_t)NR * KA * 2);
  bf16* wbwgT  = (bf16*)carve((size_t)1024 * 512 * 2);
  bf16* w1T    = (bf16*)carve((size_t)256 * 512 * 2);
  float* sWa   = (float*)carve(512 * 4);
  float* sWe   = (float*)carve(512 * 4);
  float* baPad = (float*)carve(1024 * 4);
  bf16* xbuf   = (bf16*)carve((size_t)TSTEPS * BATCH * 64 * 2);
  float* tdT   = (float*)carve((size_t)TSTEPS * BATCH * 4);
  float* cbuf  = (float*)carve((size_t)BATCH * HDIM * 4);
  bf16* hbuf   = (bf16*)carve((size_t)BATCH * HDIM * 2);
  bf16* hcur   = (bf16*)carve((size_t)BATCH * HDIM * 2);
  bf16* hWbG   = (bf16*)carve((size_t)BATCH * 1024 * 2);
  bf16* histWa = (bf16*)carve((size_t)16 * BATCH * HDIM * 2);
  bf16* histWe = (bf16*)carve((size_t)16 * BATCH * HDIM * 2);
  bf16* hd1    = (bf16*)carve((size_t)BATCH * 256 * 2);

  // ---- setup ----
  build_x_kernel<<<(TSTEPS * BATCH * 64) / 256, 256, 0, stream>>>(inputs, xbuf, tdT);
  pack_wcombT_kernel<<<(NR * KA + 255) / 256, 256, 0, stream>>>(Wx, Uh, Wt, WxT, Wa, We, wcombT);
  pack_t_kernel<<<(512 * 512) / 256, 256, 0, stream>>>(Wb, wbwgT, 512, 512);
  pack_t_kernel<<<(512 * 512) / 256, 256, 0, stream>>>(Wg, wbwgT + (size_t)512 * 512, 512, 512);
  pack_t_kernel<<<(256 * 512) / 256, 256, 0, stream>>>(W1, w1T, 256, 512);
  setup_misc_kernel<<<1, 512, 0, stream>>>(init_proj, Wa, We, ba, sWa, sWe, baPad);
  zero_state_kernel<<<(BATCH * HDIM) / 256, 256, 0, stream>>>(cbuf, hbuf);

  // ---- recurrence: 3 kernels per step (R8 structure, upgraded gemm2) ----
  for (int t = 0; t < TSTEPS; ++t) {
    bf16* waSlot = histWa + (size_t)((t + 15) & 15) * BATCH * HDIM;
    bf16* weSlot = histWe + (size_t)((t + 15) & 15) * BATCH * HDIM;
    gemm1_fused<<<1024, 256, 0, stream>>>(
        xbuf + (size_t)t * BATCH * 64, hbuf, wcombT, tdT + (size_t)t * BATCH, bv, WtT, bT,
        cbuf, hcur, waSlot, weSlot);
    gemm2_kernel<<<1024, 256, 0, stream>>>(hcur, wbwgT, baPad, hWbG);
    attention_kernel<<<BATCH / 4, 256, 0, stream>>>(hWbG, sWa, sWe, va, bh, histWa, histWe,
                                                    hbuf, t);
  }

  // ---- head ----
  gemm_glds_kernel<64, 128><<<dim3(256 / 128, BATCH / 64), 256, 0, stream>>>(
      hbuf, 512, 512, hbuf, 512, w1T, 512, 3, nullptr, 0, nullptr, hd1, 256, b1);
  head_kernel<<<BATCH / 256, 256, 0, stream>>>(hd1, W2, b2, W3, b3, out);
}

// Round 11
// 1164.670 us; speedup vs baseline: 12.1364x; 1.0269x over previous
//
#include <hip/hip_runtime.h>
#include <hip/hip_bf16.h>

typedef __bf16 bf16;
typedef __attribute__((ext_vector_type(8))) __bf16 bf16x8;
typedef __attribute__((ext_vector_type(4))) float floatx4;

#define HDIM 512
#define BATCH 4096
#define TSTEPS 16
#define KA 576      // A width: 63 x-feats + td + 512 h
#define NR 3584     // GEMM1 out cols: 7 roles x 512 h (no pad role)

typedef const __attribute__((address_space(1))) void gvoid;
typedef __attribute__((address_space(3))) void svoid;

__device__ __forceinline__ float ftanh(float x) {
  float xx = fminf(fmaxf(x, -15.f), 15.f);
  float t = __expf(2.f * xx);
  return (t - 1.f) / (t + 1.f);
}
__device__ __forceinline__ float fsigm(float x) { return 1.0f / (1.0f + __expf(-x)); }

__device__ __forceinline__ float waveAllSum(float v) {
#pragma unroll
  for (int off = 32; off > 0; off >>= 1) v += __shfl_xor(v, off, 64);
  return v;
}

// ---------------------------------------------------------------------------
// Fused GEMM1 + gates. A = [x_t(63) | td | h(512)], B = role-interleaved WcombT
// with NO pad role: packed col n -> blk=n/112, role=(n%112)>>4, h=blk*16+(n&15).
// BM=128, BN=112, BK=64. Waves 1x4 in m (WM=32): TM=2, TN=7 -> all 7 roles of
// (m,h) land in one lane's acc[i][0..6][r]; no cross-wave exchange, no extra
// barriers. LDS 30 KB -> 4 blocks/CU. Same XOR chunk swizzle (proven 0-conflict).
// Roles: 0..3 = zi,zf,zo,zc (td*Wt folded via A col63), 4 = tg, 5 = hWa, 6 = hWe.
// ---------------------------------------------------------------------------
__global__ __launch_bounds__(256, 4)
void gemm1_fused(const bf16* __restrict__ A1, const bf16* __restrict__ A2,
                 const bf16* __restrict__ BT,
                 const float* __restrict__ tdT, const float* __restrict__ bvec,
                 const float* __restrict__ WtT, const float* __restrict__ bT,
                 float* __restrict__ cbuf, bf16* __restrict__ hcur,
                 bf16* __restrict__ waSlot, bf16* __restrict__ weSlot) {
  constexpr int BM = 128, BN = 112, BK = 64;
  constexpr int TM = 2, TN = 7;
  __shared__ __align__(16) bf16 As[BM * BK];  // 16 KB
  __shared__ __align__(16) bf16 Bs[BN * BK];  // 14 KB

  const int tid = threadIdx.x;
  const int lane = tid & 63;
  const int wv = tid >> 6;     // m-quadrant (WM=32 each)
  const int quad = lane >> 4;
  const int lr = lane & 15;
  const int bid = blockIdx.x;
  const int xcd = bid & 7;
  const int p = bid >> 3;
  const int n_idx = (xcd << 2) | (p >> 5);  // [0,32): h-group
  const int m_idx = p & 31;
  const int m0 = m_idx * BM;
  const int n0 = n_idx * BN;
  const int g8 = lane >> 3;
  const int cl = (lane & 7) ^ g8;  // logical chunk fetched (phys = lc ^ (row&7))

  floatx4 acc[TM][TN];
#pragma unroll
  for (int i = 0; i < TM; ++i)
#pragma unroll
    for (int j = 0; j < TN; ++j) {
      acc[i][j][0] = 0.f; acc[i][j][1] = 0.f; acc[i][j][2] = 0.f; acc[i][j][3] = 0.f;
    }

  for (int kt = 0; kt < KA / BK; ++kt) {
    const int kb = kt * BK;
    __syncthreads();
#pragma unroll
    for (int s = 0; s < 4; ++s) {  // A: 16 groups of 8 rows, 4 per wave
      const int g = wv * 4 + s;
      const int r = g * 8 + g8;
      const int col = kb + cl * 8;
      const bf16* src = (kt == 0) ? (A1 + (size_t)(m0 + r) * 64 + col)
                                  : (A2 + (size_t)(m0 + r) * 512 + (col - 64));
      __builtin_amdgcn_global_load_lds((gvoid*)src, (svoid*)&As[g * 512], 16, 0, 0);
    }
#pragma unroll
    for (int s = 0; s < 4; ++s) {  // B: 14 groups of 8 rows; waves 0-2 take 4, wave 3 takes 2
      const int g = wv * 4 + s;
      if (g < 14) {
        const int r = g * 8 + g8;
        const bf16* src = BT + (size_t)(n0 + r) * KA + kb + cl * 8;
        __builtin_amdgcn_global_load_lds((gvoid*)src, (svoid*)&Bs[g * 512], 16, 0, 0);
      }
    }
    __syncthreads();
#pragma unroll
    for (int s = 0; s < 2; ++s) {  // two K=32 half-steps
      const int lc = s * 4 + quad;
      bf16x8 afr[TM];
      bf16x8 bfr[TN];
#pragma unroll
      for (int i = 0; i < TM; ++i) {
        const int r = wv * 32 + i * 16 + lr;
        afr[i] = *reinterpret_cast<const bf16x8*>(&As[r * 64 + ((lc ^ (r & 7)) << 3)]);
      }
#pragma unroll
      for (int j = 0; j < TN; ++j) {
        const int r = j * 16 + lr;
        bfr[j] = *reinterpret_cast<const bf16x8*>(&Bs[r * 64 + ((lc ^ (r & 7)) << 3)]);
      }
#pragma unroll
      for (int i = 0; i < TM; ++i)
#pragma unroll
        for (int j = 0; j < TN; ++j)
          acc[i][j] = __builtin_amdgcn_mfma_f32_16x16x32_bf16(afr[i], bfr[j], acc[i][j], 0, 0, 0);
    }
  }

  // ---- fused gate epilogue: all roles in-lane ----
  const int hcol = n_idx * 16 + lr;
  const float bvi = bvec[hcol], bvf = bvec[512 + hcol];
  const float bvo = bvec[1024 + hcol], bvc = bvec[1536 + hcol];
  const float wtt = WtT[hcol], bt_ = bT[hcol];
#pragma unroll
  for (int i = 0; i < TM; ++i) {
#pragma unroll
    for (int r = 0; r < 4; ++r) {
      const int m = m0 + wv * 32 + i * 16 + quad * 4 + r;
      const float td = tdT[m];
      const size_t o = (size_t)m * 512 + hcol;
      const float c_old = cbuf[o];
      const float i_ = fsigm(acc[i][0][r] + bvi);
      const float f_ = fsigm(acc[i][1][r] + bvf);
      const float o_ = fsigm(acc[i][2][r] + bvo);
      const float ch = ftanh(acc[i][3][r] + bvc);
      const float tg = fsigm(acc[i][4][r] + fsigm(td * wtt) + bt_);
      const float cn = f_ * c_old + (i_ + tg) * ch;
      cbuf[o] = cn;
      hcur[o] = (bf16)(o_ * ftanh(cn));
      waSlot[o] = (bf16)acc[i][5][r];
      weSlot[o] = (bf16)acc[i][6][r];
    }
  }
}

// ---------------------------------------------------------------------------
// GEMM2: hcur[4096x512] @ wbwgT^T -> hWbG bf16 [4096x1024] (+baPad).
// 1024 blocks of 64x64 tiles, BK=64, 4 blocks/CU (R10 proven).
// ---------------------------------------------------------------------------
__global__ __launch_bounds__(256, 4)
void gemm2_kernel(const bf16* __restrict__ hcur, const bf16* __restrict__ wbwgT,
                  const float* __restrict__ baPad, bf16* __restrict__ hWbG) {
  __shared__ __align__(16) bf16 As[64 * 64];  // 8 KB
  __shared__ __align__(16) bf16 Bs[64 * 64];  // 8 KB

  const int tid = threadIdx.x;
  const int lane = tid & 63;
  const int wv = tid >> 6;
  const int wy = wv >> 1;
  const int wx = wv & 1;
  const int quad = lane >> 4;
  const int lr = lane & 15;
  const int bid = blockIdx.x;
  const int m0 = (bid >> 4) * 64;
  const int n0 = (bid & 15) * 64;
  const int g8 = lane >> 3;
  const int cl = (lane & 7) ^ g8;

  floatx4 acc[2][2];
#pragma unroll
  for (int i = 0; i < 2; ++i)
#pragma unroll
    for (int j = 0; j < 2; ++j) {
      acc[i][j][0] = 0.f; acc[i][j][1] = 0.f; acc[i][j][2] = 0.f; acc[i][j][3] = 0.f;
    }

  for (int kt = 0; kt < 8; ++kt) {
    const int kb = kt * 64;
    __syncthreads();
#pragma unroll
    for (int s = 0; s < 2; ++s) {
      const int g = wv * 2 + s;
      const int r = g * 8 + g8;
      const bf16* src = hcur + (size_t)(m0 + r) * 512 + kb + cl * 8;
      __builtin_amdgcn_global_load_lds((gvoid*)src, (svoid*)&As[g * 512], 16, 0, 0);
    }
#pragma unroll
    for (int s = 0; s < 2; ++s) {
      const int g = wv * 2 + s;
      const int r = g * 8 + g8;
      const bf16* src = wbwgT + (size_t)(n0 + r) * 512 + kb + cl * 8;
      __builtin_amdgcn_global_load_lds((gvoid*)src, (svoid*)&Bs[g * 512], 16, 0, 0);
    }
    __syncthreads();
#pragma unroll
    for (int s = 0; s < 2; ++s) {
      const int lc = s * 4 + quad;
      bf16x8 afr[2];
      bf16x8 bfr[2];
#pragma unroll
      for (int i = 0; i < 2; ++i) {
        const int r = wy * 32 + i * 16 + lr;
        afr[i] = *reinterpret_cast<const bf16x8*>(&As[r * 64 + ((lc ^ (r & 7)) << 3)]);
      }
#pragma unroll
      for (int j = 0; j < 2; ++j) {
        const int r = wx * 32 + j * 16 + lr;
        bfr[j] = *reinterpret_cast<const bf16x8*>(&Bs[r * 64 + ((lc ^ (r & 7)) << 3)]);
      }
#pragma unroll
      for (int i = 0; i < 2; ++i)
#pragma unroll
        for (int j = 0; j < 2; ++j)
          acc[i][j] = __builtin_amdgcn_mfma_f32_16x16x32_bf16(afr[i], bfr[j], acc[i][j], 0, 0, 0);
    }
  }

#pragma unroll
  for (int i = 0; i < 2; ++i) {
#pragma unroll
    for (int j = 0; j < 2; ++j) {
      const int n = n0 + wx * 32 + j * 16 + lr;
      const float bb = baPad[n];
#pragma unroll
      for (int r = 0; r < 4; ++r) {
        const int m = m0 + wy * 32 + i * 16 + quad * 4 + r;
        hWbG[(size_t)m * 1024 + n] = (bf16)(acc[i][j][r] + bb);
      }
    }
  }
}

// ---------------------------------------------------------------------------
// Generic MFMA GEMM (glds staging, BK=32 swizzle) — head only.
// mode 3: relu(v+cBias2) -> bf16 outBa
// ---------------------------------------------------------------------------
template <int BM, int BN>
__global__ __launch_bounds__(256)
void gemm_glds_kernel(const bf16* __restrict__ A1, int ld1, int K1,
                      const bf16* __restrict__ A2, int ld2,
                      const bf16* __restrict__ BT, int K, int mode,
                      float* __restrict__ outF, int ldF, const float* __restrict__ colBias,
                      bf16* __restrict__ outBa, int ldBa, const float* __restrict__ cBias2) {
  constexpr int BK = 32;
  constexpr int WM = BM / 2;
  constexpr int WN = BN / 2;
  constexpr int TM = WM / 16;
  constexpr int TN = WN / 16;
  constexpr int AIW = BM / 64;
  constexpr int BIW = BN / 64;
  __shared__ __align__(16) bf16 As[BM * BK];
  __shared__ __align__(16) bf16 Bs[BN * BK];

  const int tid = threadIdx.x;
  const int lane = tid & 63;
  const int wv = tid >> 6;
  const int wy = wv >> 1;
  const int wx = wv & 1;
  const int quad = lane >> 4;
  const int lr = lane & 15;
  const int m0 = blockIdx.y * BM;
  const int n0 = blockIdx.x * BN;
  const int sw = quad ^ ((lr >> 1) & 3);
  const int srow = lane >> 2;
  const int cl = (lane & 3) ^ ((lane >> 3) & 3);

  floatx4 acc[TM][TN];
#pragma unroll
  for (int i = 0; i < TM; ++i)
#pragma unroll
    for (int j = 0; j < TN; ++j) {
      acc[i][j][0] = 0.f; acc[i][j][1] = 0.f; acc[i][j][2] = 0.f; acc[i][j][3] = 0.f;
    }

  const int kTiles = K / BK;
  for (int kt = 0; kt < kTiles; ++kt) {
    const int kb = kt * BK;
    __syncthreads();
#pragma unroll
    for (int s = 0; s < AIW; ++s) {
      const int rbase = (wv * AIW + s) * 16;
      const int r = rbase + srow;
      const int col = kb + cl * 8;
      const bf16* src = (col < K1) ? (A1 + (size_t)(m0 + r) * ld1 + col)
                                   : (A2 + (size_t)(m0 + r) * ld2 + (col - K1));
      __builtin_amdgcn_global_load_lds((gvoid*)src, (svoid*)&As[rbase * BK], 16, 0, 0);
    }
#pragma unroll
    for (int s = 0; s < BIW; ++s) {
      const int rbase = (wv * BIW + s) * 16;
      const int r = rbase + srow;
      const bf16* src = BT + (size_t)(n0 + r) * K + kb + cl * 8;
      __builtin_amdgcn_global_load_lds((gvoid*)src, (svoid*)&Bs[rbase * BK], 16, 0, 0);
    }
    __syncthreads();
    bf16x8 afr[TM];
    bf16x8 bfr[TN];
#pragma unroll
    for (int i = 0; i < TM; ++i)
      afr[i] = *reinterpret_cast<const bf16x8*>(&As[(wy * WM + i * 16 + lr) * BK + sw * 8]);
#pragma unroll
    for (int j = 0; j < TN; ++j)
      bfr[j] = *reinterpret_cast<const bf16x8*>(&Bs[(wx * WN + j * 16 + lr) * BK + sw * 8]);
#pragma unroll
    for (int i = 0; i < TM; ++i)
#pragma unroll
      for (int j = 0; j < TN; ++j)
        acc[i][j] = __builtin_amdgcn_mfma_f32_16x16x32_bf16(afr[i], bfr[j], acc[i][j], 0, 0, 0);
  }

#pragma unroll
  for (int i = 0; i < TM; ++i) {
#pragma unroll
    for (int j = 0; j < TN; ++j) {
#pragma unroll
      for (int r = 0; r < 4; ++r) {
        int m = m0 + wy * WM + i * 16 + quad * 4 + r;
        int n = n0 + wx * WN + j * 16 + lr;
        float v = acc[i][j][r];
        if (mode == 0) {
          if (colBias != nullptr) v += colBias[n];
          outF[(size_t)m * ldF + n] = v;
        } else {  // mode 3
          v += cBias2[n];
          v = v > 0.f ? v : 0.f;
          outBa[(size_t)m * ldBa + n] = (bf16)v;
        }
      }
    }
  }
}

// ---------------------------------------------------------------------------
// Setup kernels (run every call; ws re-poisoned by harness)
// ---------------------------------------------------------------------------
// Packed WcombT[n][k], n<3584: blk=n/112, role=(n%112)>>4, h=blk*16+(n&15)
__global__ void pack_wcombT_kernel(const float* __restrict__ Wx, const float* __restrict__ Uh,
                                   const float* __restrict__ Wt, const float* __restrict__ WxT,
                                   const float* __restrict__ Wa, const float* __restrict__ We,
                                   bf16* __restrict__ out) {
  int idx = blockIdx.x * 256 + threadIdx.x;
  if (idx >= NR * KA) return;
  int n = idx / KA;
  int k = idx - n * KA;
  int blk = n / 112;
  int rem = n - blk * 112;
  int role = rem >> 4;
  int h = blk * 16 + (rem & 15);
  float v = 0.f;
  if (k < 63) {
    if (role < 4) v = Wx[k * 2048 + role * 512 + h];
    else if (role == 4) v = WxT[k * 512 + h];
  } else if (k == 63) {
    if (role < 3) v = Wt[role * 512 + h];
  } else {
    int kh = k - 64;
    if (role < 4) v = Uh[kh * 2048 + role * 512 + h];
    else if (role == 5) v = Wa[kh * 512 + h];
    else if (role == 6) v = We[kh * 512 + h];
  }
  out[idx] = (bf16)v;
}

__global__ void pack_t_kernel(const float* __restrict__ in, bf16* __restrict__ out, int N, int K) {
  int idx = blockIdx.x * 256 + threadIdx.x;
  if (idx >= N * K) return;
  int n = idx / K;
  int j = idx - n * K;
  out[idx] = (bf16)in[(size_t)j * N + n];
}

__global__ __launch_bounds__(512)
void setup_misc_kernel(const float* __restrict__ init_proj, const float* __restrict__ Wa,
                       const float* __restrict__ We, const float* __restrict__ ba,
                       float* __restrict__ sWa, float* __restrict__ sWe,
                       float* __restrict__ baPad) {
  __shared__ float s_sh[HDIM];
  int h = threadIdx.x;
  float acc = 0.f;
  for (int f = 0; f < 64; ++f) acc += init_proj[f * HDIM + h];
  s_sh[h] = acc;
  baPad[h] = ba[h];
  baPad[HDIM + h] = 0.f;
  __syncthreads();
  float a2 = 0.f, a3 = 0.f;
  for (int i = 0; i < HDIM; ++i) {
    a2 += s_sh[i] * Wa[i * HDIM + h];
    a3 += s_sh[i] * We[i * HDIM + h];
  }
  sWa[h] = a2;
  sWe[h] = a3;
}

__global__ void zero_state_kernel(float* __restrict__ c, bf16* __restrict__ h) {
  int idx = blockIdx.x * 256 + threadIdx.x;
  if (idx >= BATCH * HDIM) return;
  c[idx] = 0.f;
  h[idx] = (bf16)0.f;
}

__global__ void build_x_kernel(const float* __restrict__ inputs, bf16* __restrict__ xbuf,
                               float* __restrict__ tdT) {
  int idx = blockIdx.x * 256 + threadIdx.x;
  if (idx >= TSTEPS * BATCH * 64) return;
  int c = idx & 63;
  int bt = idx >> 6;
  int t = bt >> 12;
  int b = bt & 4095;
  float v;
  if (c < 63) {
    v = inputs[(size_t)b * 1024 + t * 64 + 1 + c];
  } else {
    v = inputs[(size_t)b * 1024 + t * 64];
    tdT[t * BATCH + b] = v;
  }
  xbuf[idx] = (bf16)v;
}

// attention + h_new epilogue; 4 waves/block, one batch row per wave
__global__ __launch_bounds__(256)
void attention_kernel(const bf16* __restrict__ hWbG,
                      const float* __restrict__ sWa, const float* __restrict__ sWe,
                      const float* __restrict__ va, const float* __restrict__ bh,
                      const bf16* __restrict__ histWa, const bf16* __restrict__ histWe,
                      bf16* __restrict__ hbuf, int k) {
  int b = blockIdx.x * 4 + (threadIdx.x >> 6);
  int lane = threadIdx.x & 63;
  float wb[8], sw_[8], vv[8];
  const bf16* wbp = hWbG + (size_t)b * 1024 + lane * 8;
  bf16x8 wbv = *reinterpret_cast<const bf16x8*>(wbp);
#pragma unroll
  for (int i = 0; i < 8; ++i) {
    wb[i] = (float)wbv[i];
    sw_[i] = sWa[lane * 8 + i];
    vv[i] = va[lane * 8 + i];
  }
  float p = 0.f;
#pragma unroll
  for (int i = 0; i < 8; ++i) p += vv[i] * ftanh(sw_[i] + wb[i]);
  float e_init = waveAllSum(p);

  float e[15];
#pragma unroll
  for (int j = 0; j < 15; ++j) {
    if (j < k) {
      bf16x8 hv = *reinterpret_cast<const bf16x8*>(
          histWa + ((size_t)j * BATCH + b) * HDIM + lane * 8);
      float q = 0.f;
#pragma unroll
      for (int i = 0; i < 8; ++i) q += vv[i] * ftanh((float)hv[i] + wb[i]);
      e[j] = waveAllSum(q);
    }
  }
  float mx = (k < 15) ? e_init : -1e30f;
#pragma unroll
  for (int j = 0; j < 15; ++j)
    if (j < k) mx = fmaxf(mx, e[j]);
  float winit = (k < 15) ? (float)(15 - k) * __expf(e_init - mx) : 0.f;
  float denom = winit;
  float w[15];
#pragma unroll
  for (int j = 0; j < 15; ++j)
    if (j < k) { w[j] = __expf(e[j] - mx); denom += w[j]; }
  float inv = 1.f / denom;
  float cx[8];
  float ai = winit * inv;
#pragma unroll
  for (int i = 0; i < 8; ++i) cx[i] = ai * sWe[lane * 8 + i];
#pragma unroll
  for (int j = 0; j < 15; ++j) {
    if (j < k) {
      bf16x8 hv = *reinterpret_cast<const bf16x8*>(
          histWe + ((size_t)j * BATCH + b) * HDIM + lane * 8);
      float aj = w[j] * inv;
#pragma unroll
      for (int i = 0; i < 8; ++i) cx[i] += aj * (float)hv[i];
    }
  }
  bf16x8 wgv = *reinterpret_cast<const bf16x8*>(wbp + 512);
  bf16x8 hnew;
#pragma unroll
  for (int i = 0; i < 8; ++i)
    hnew[i] = (bf16)ftanh(cx[i] + (float)wgv[i] + bh[lane * 8 + i]);
  *reinterpret_cast<bf16x8*>(hbuf + (size_t)b * HDIM + lane * 8) = hnew;
}

__global__ __launch_bounds__(256)
void head_kernel(const bf16* __restrict__ hd1, const float* __restrict__ W2,
                 const float* __restrict__ b2, const float* __restrict__ W3,
                 const float* __restrict__ b3, float* __restrict__ out) {
  __shared__ float W2s[256 * 32];
  __shared__ float b2s[32];
  __shared__ float W3s[64];
  __shared__ float b3s[2];
  for (int i = threadIdx.x; i < 256 * 32; i += 256) W2s[i] = W2[i];
  if (threadIdx.x < 32) b2s[threadIdx.x] = b2[threadIdx.x];
  if (threadIdx.x < 64) W3s[threadIdx.x] = W3[threadIdx.x];
  if (threadIdx.x < 2) b3s[threadIdx.x] = b3[threadIdx.x];
  __syncthreads();
  int row = blockIdx.x * 256 + threadIdx.x;
  float acc[32];
#pragma unroll
  for (int j = 0; j < 32; ++j) acc[j] = b2s[j];
  const bf16* hp = hd1 + (size_t)row * 256;
  for (int i = 0; i < 256; ++i) {
    float hv = (float)hp[i];
#pragma unroll
    for (int j = 0; j < 32; ++j) acc[j] += hv * W2s[i * 32 + j];
  }
  float l0 = b3s[0], l1 = b3s[1];
#pragma unroll
  for (int j = 0; j < 32; ++j) {
    float r = fmaxf(acc[j], 0.f);
    l0 += r * W3s[j * 2];
    l1 += r * W3s[j * 2 + 1];
  }
  float m = fmaxf(l0, l1);
  float e0 = __expf(l0 - m), e1 = __expf(l1 - m);
  float inv = 1.f / (e0 + e1);
  out[(size_t)row * 2] = e0 * inv;
  out[(size_t)row * 2 + 1] = e1 * inv;
}

// ---------------------------------------------------------------------------
extern "C" void kernel_launch(void* const* d_in, const int* in_sizes, int n_in,
                              void* d_out, int out_size, void* d_ws, size_t ws_size,
                              hipStream_t stream) {
  const float* inputs    = (const float*)d_in[0];
  const float* init_proj = (const float*)d_in[1];
  const float* Wx  = (const float*)d_in[3];
  const float* Uh  = (const float*)d_in[4];
  const float* Wt  = (const float*)d_in[5];
  const float* bv  = (const float*)d_in[6];
  const float* WxT = (const float*)d_in[7];
  const float* WtT = (const float*)d_in[8];
  const float* bT  = (const float*)d_in[9];
  const float* Wa  = (const float*)d_in[10];
  const float* Wb  = (const float*)d_in[11];
  const float* va  = (const float*)d_in[12];
  const float* ba  = (const float*)d_in[13];
  const float* We  = (const float*)d_in[14];
  const float* Wg  = (const float*)d_in[15];
  const float* bh  = (const float*)d_in[16];
  const float* W1  = (const float*)d_in[17];
  const float* b1  = (const float*)d_in[18];
  const float* W2  = (const float*)d_in[19];
  const float* b2  = (const float*)d_in[20];
  const float* W3  = (const float*)d_in[21];
  const float* b3  = (const float*)d_in[22];
  float* out = (float*)d_out;

  char* wp = (char*)d_ws;
  auto carve = [&](size_t bytes) -> void* {
    void* p = (void*)wp;
    wp += (bytes + 255) & ~(size_t)255;
    return p;
  };
  bf16* wcombT = (bf16*)carve((size_t)NR * KA * 2);
  bf16* wbwgT  = (bf16*)carve((size_t)1024 * 512 * 2);
  bf16* w1T    = (bf16*)carve((size_t)256 * 512 * 2);
  float* sWa   = (float*)carve(512 * 4);
  float* sWe   = (float*)carve(512 * 4);
  float* baPad = (float*)carve(1024 * 4);
  bf16* xbuf   = (bf16*)carve((size_t)TSTEPS * BATCH * 64 * 2);
  float* tdT   = (float*)carve((size_t)TSTEPS * BATCH * 4);
  float* cbuf  = (float*)carve((size_t)BATCH * HDIM * 4);
  bf16* hbuf   = (bf16*)carve((size_t)BATCH * HDIM * 2);
  bf16* hcur   = (bf16*)carve((size_t)BATCH * HDIM * 2);
  bf16* hWbG   = (bf16*)carve((size_t)BATCH * 1024 * 2);
  bf16* histWa = (bf16*)carve((size_t)16 * BATCH * HDIM * 2);
  bf16* histWe = (bf16*)carve((size_t)16 * BATCH * HDIM * 2);
  bf16* hd1    = (bf16*)carve((size_t)BATCH * 256 * 2);

  // ---- setup ----
  build_x_kernel<<<(TSTEPS * BATCH * 64) / 256, 256, 0, stream>>>(inputs, xbuf, tdT);
  pack_wcombT_kernel<<<(NR * KA + 255) / 256, 256, 0, stream>>>(Wx, Uh, Wt, WxT, Wa, We, wcombT);
  pack_t_kernel<<<(512 * 512) / 256, 256, 0, stream>>>(Wb, wbwgT, 512, 512);
  pack_t_kernel<<<(512 * 512) / 256, 256, 0, stream>>>(Wg, wbwgT + (size_t)512 * 512, 512, 512);
  pack_t_kernel<<<(256 * 512) / 256, 256, 0, stream>>>(W1, w1T, 256, 512);
  setup_misc_kernel<<<1, 512, 0, stream>>>(init_proj, Wa, We, ba, sWa, sWe, baPad);
  zero_state_kernel<<<(BATCH * HDIM) / 256, 256, 0, stream>>>(cbuf, hbuf);

  // ---- recurrence: 3 kernels per step ----
  for (int t = 0; t < TSTEPS; ++t) {
    bf16* waSlot = histWa + (size_t)((t + 15) & 15) * BATCH * HDIM;
    bf16* weSlot = histWe + (size_t)((t + 15) & 15) * BATCH * HDIM;
    gemm1_fused<<<1024, 256, 0, stream>>>(
        xbuf + (size_t)t * BATCH * 64, hbuf, wcombT, tdT + (size_t)t * BATCH, bv, WtT, bT,
        cbuf, hcur, waSlot, weSlot);
    gemm2_kernel<<<1024, 256, 0, stream>>>(hcur, wbwgT, baPad, hWbG);
    attention_kernel<<<BATCH / 4, 256, 0, stream>>>(hWbG, sWa, sWe, va, bh, histWa, histWe,
                                                    hbuf, t);
  }

  // ---- head ----
  gemm_glds_kernel<64, 128><<<dim3(256 / 128, BATCH / 64), 256, 0, stream>>>(
      hbuf, 512, 512, hbuf, 512, w1T, 512, 3, nullptr, 0, nullptr, hd1, 256, b1);
  head_kernel<<<BATCH / 256, 256, 0, stream>>>(hd1, W2, b2, W3, b3, out);
}